// Round 1
// 726.381 us; speedup vs baseline: 1.8663x; 1.8663x over previous
//
#include <hip/hip_runtime.h>
#include <cstdint>
#include <cstddef>

// FullLinearAttention — decomposed pipeline, all-bf16 compute with
// global_load_lds staging (m97 structure) for every GEMM.
//   K0  cvt:    xb=bf16(x) -> O[0,64M); wbq=bf16(w_qkv) -> O[64M,70M);
//               wbo=bf16(w_out) -> W1[0,2M)
//   K1  kv GEMM: [32768,2048]=xb@wbq[1024:3072]^T, elu on K half ->
//               kb=A[0,64M), vb=A[64M,128M)
//   K2  fold:   per (bh,sch) partial kv/ksum -> Pp O[72M,104M), KsP O[104M,104.5M)
//   K3  reduce: 32 partials -> kvb,ksb (bf16) in W1[2M,2.51M)
//   K4  q GEMM: qb=elu(xb@wbq[0:1024]^T) -> A[0,64M)  (kb dead)
//   K5  attn:   (q@kv)/max(q.ksum,1e-6) -> attn bf16 A[64M,128M) (vb dead)
//   K6  out GEMM: attn@wbo^T -> f32 directly into d_out (all O scratch dead)

typedef __bf16 bf16;
typedef __bf16 bf16x8 __attribute__((ext_vector_type(8)));
typedef __bf16 bf16x4 __attribute__((ext_vector_type(4)));
typedef float  f32x4  __attribute__((ext_vector_type(4)));

#define MFMA(a, b, c) __builtin_amdgcn_mfma_f32_16x16x32_bf16((a), (b), (c), 0, 0, 0)

__device__ __forceinline__ void gld_lds16(const bf16* g, bf16* l) {
  __builtin_amdgcn_global_load_lds(
      (const __attribute__((address_space(1))) void*)g,
      (__attribute__((address_space(3))) void*)l, 16, 0, 0);
}

// ---------------------------------------------------------------- convert ---
__global__ __launch_bounds__(256) void cvt_bf16(const float* __restrict__ src,
                                                bf16* __restrict__ dst, int n8) {
  const int stride = gridDim.x * 256;
  for (int i = blockIdx.x * 256 + threadIdx.x; i < n8; i += stride) {
    const float* p = src + (size_t)i * 8;
    f32x4 a = *(const f32x4*)p;
    f32x4 b = *(const f32x4*)(p + 4);
    bf16x8 r;
    r[0] = (bf16)a[0]; r[1] = (bf16)a[1]; r[2] = (bf16)a[2]; r[3] = (bf16)a[3];
    r[4] = (bf16)b[0]; r[5] = (bf16)b[1]; r[6] = (bf16)b[2]; r[7] = (bf16)b[3];
    *(bf16x8*)(dst + (size_t)i * 8) = r;
  }
}

// ------------------------------------------------------- GEMM, bf16 output --
// C[M,N] = A[M,1024] @ B[N,1024]^T.  grid.x = N/128 tiles (B), grid.y = M/128.
// Column-blocks with blockIdx.x < nelu get elu+1 and go to out0 at col rowB;
// the rest go raw to out1 at col rowB-1024.
__global__ __launch_bounds__(256) void gemm_bf16o(
    const bf16* __restrict__ A, const bf16* __restrict__ B,
    bf16* __restrict__ out0, bf16* __restrict__ out1, int nelu) {
  __shared__ __align__(16) bf16 As[128 * 32];
  __shared__ __align__(16) bf16 Bs[128 * 32];
  const int tid = threadIdx.x, lane = tid & 63, wave = tid >> 6;
  const int grp = lane >> 4, mlane = lane & 15;
  const int rowB = blockIdx.x * 128, rowA = blockIdx.y * 128;
  const int r0 = tid >> 2, kc0 = (tid & 3) * 8;
  const int m0 = (wave >> 1) * 64, n0 = (wave & 1) * 64;

  const bf16* ga0 = A + (size_t)(rowA + r0) * 1024 + kc0;
  const bf16* ga1 = ga0 + (size_t)64 * 1024;
  const bf16* gb0 = B + (size_t)(rowB + r0) * 1024 + kc0;
  const bf16* gb1 = gb0 + (size_t)64 * 1024;

  const f32x4 zero = {0.f, 0.f, 0.f, 0.f};
  f32x4 acc[4][4];
#pragma unroll
  for (int i = 0; i < 4; ++i)
#pragma unroll
    for (int j = 0; j < 4; ++j) acc[i][j] = zero;

  for (int k0 = 0; k0 < 1024; k0 += 32) {
    gld_lds16(ga0, &As[tid * 8]);
    gld_lds16(ga1, &As[2048 + tid * 8]);
    gld_lds16(gb0, &Bs[tid * 8]);
    gld_lds16(gb1, &Bs[2048 + tid * 8]);
    ga0 += 32; ga1 += 32; gb0 += 32; gb1 += 32;
    __syncthreads();  // drains vmcnt -> LDS tiles complete
    bf16x8 af[4], bfr[4];
#pragma unroll
    for (int i = 0; i < 4; ++i)
      af[i] = *(const bf16x8*)&As[(m0 + i * 16 + mlane) * 32 + grp * 8];
#pragma unroll
    for (int j = 0; j < 4; ++j)
      bfr[j] = *(const bf16x8*)&Bs[(n0 + j * 16 + mlane) * 32 + grp * 8];
#pragma unroll
    for (int i = 0; i < 4; ++i)
#pragma unroll
      for (int j = 0; j < 4; ++j) acc[i][j] = MFMA(af[i], bfr[j], acc[i][j]);
    __syncthreads();
  }

  const bool iselu = blockIdx.x < (unsigned)nelu;
  bf16* dst = iselu ? out0 : out1;
  const int cbase = iselu ? rowB : rowB - 1024;
#pragma unroll
  for (int i = 0; i < 4; ++i)
#pragma unroll
    for (int j = 0; j < 4; ++j)
#pragma unroll
      for (int r = 0; r < 4; ++r) {
        float v = acc[i][j][r];
        if (iselu) v = (v > 0.f) ? (v + 1.f) : __expf(v);
        dst[(size_t)(rowA + m0 + i * 16 + grp * 4 + r) * 1024 +
            cbase + n0 + j * 16 + mlane] = (bf16)v;
      }
}

// -------------------------------------------------------- GEMM, f32 output --
__global__ __launch_bounds__(256) void gemm_f32o(
    const bf16* __restrict__ A, const bf16* __restrict__ B,
    float* __restrict__ C) {
  __shared__ __align__(16) bf16 As[128 * 32];
  __shared__ __align__(16) bf16 Bs[128 * 32];
  const int tid = threadIdx.x, lane = tid & 63, wave = tid >> 6;
  const int grp = lane >> 4, mlane = lane & 15;
  const int rowB = blockIdx.x * 128, rowA = blockIdx.y * 128;
  const int r0 = tid >> 2, kc0 = (tid & 3) * 8;
  const int m0 = (wave >> 1) * 64, n0 = (wave & 1) * 64;

  const bf16* ga0 = A + (size_t)(rowA + r0) * 1024 + kc0;
  const bf16* ga1 = ga0 + (size_t)64 * 1024;
  const bf16* gb0 = B + (size_t)(rowB + r0) * 1024 + kc0;
  const bf16* gb1 = gb0 + (size_t)64 * 1024;

  const f32x4 zero = {0.f, 0.f, 0.f, 0.f};
  f32x4 acc[4][4];
#pragma unroll
  for (int i = 0; i < 4; ++i)
#pragma unroll
    for (int j = 0; j < 4; ++j) acc[i][j] = zero;

  for (int k0 = 0; k0 < 1024; k0 += 32) {
    gld_lds16(ga0, &As[tid * 8]);
    gld_lds16(ga1, &As[2048 + tid * 8]);
    gld_lds16(gb0, &Bs[tid * 8]);
    gld_lds16(gb1, &Bs[2048 + tid * 8]);
    ga0 += 32; ga1 += 32; gb0 += 32; gb1 += 32;
    __syncthreads();
    bf16x8 af[4], bfr[4];
#pragma unroll
    for (int i = 0; i < 4; ++i)
      af[i] = *(const bf16x8*)&As[(m0 + i * 16 + mlane) * 32 + grp * 8];
#pragma unroll
    for (int j = 0; j < 4; ++j)
      bfr[j] = *(const bf16x8*)&Bs[(n0 + j * 16 + mlane) * 32 + grp * 8];
#pragma unroll
    for (int i = 0; i < 4; ++i)
#pragma unroll
      for (int j = 0; j < 4; ++j) acc[i][j] = MFMA(af[i], bfr[j], acc[i][j]);
    __syncthreads();
  }

#pragma unroll
  for (int i = 0; i < 4; ++i)
#pragma unroll
    for (int j = 0; j < 4; ++j)
#pragma unroll
      for (int r = 0; r < 4; ++r)
        C[(size_t)(rowA + m0 + i * 16 + grp * 4 + r) * 1024 +
          rowB + n0 + j * 16 + mlane] = acc[i][j][r];
}

// ------------------------------------------------------------------- fold ---
// grid (bh=64, sch=32); block folds 256 s-rows of K~,V into one 64x64 partial.
// LDS tiles padded to stride 68 elems: lane-groups (rows +8 apart) hit bank
// sets {0,16,0,16} -> worst 2-way (free per m136) on the scalar frag reads.
__global__ __launch_bounds__(256) void fold_kv(
    const bf16* __restrict__ kb, const bf16* __restrict__ vb,
    float* __restrict__ Pp, float* __restrict__ KsP) {
  __shared__ __align__(16) char smem[69632];
  bf16* Kt = (bf16*)smem;            // [256][68]
  bf16* Vt = (bf16*)(smem + 34816);  // [256][68]
  const int bh = blockIdx.x, sch = blockIdx.y;
  const int b = bh >> 4, h = bh & 15;
  const int tid = threadIdx.x, lane = tid & 63, wave = tid >> 6;
  const int grp = lane >> 4, mlane = lane & 15;
  const int rr = tid >> 3, cc = (tid & 7) * 8;

#pragma unroll
  for (int p = 0; p < 8; ++p) {
    const int r = p * 32 + rr;
    const size_t go = (size_t)(b * 8192 + sch * 256 + r) * 1024 + h * 64 + cc;
    bf16x8 k8 = *(const bf16x8*)(kb + go);
    bf16x8 v8 = *(const bf16x8*)(vb + go);
    bf16x4 klo = {k8[0], k8[1], k8[2], k8[3]}, khi = {k8[4], k8[5], k8[6], k8[7]};
    bf16x4 vlo = {v8[0], v8[1], v8[2], v8[3]}, vhi = {v8[4], v8[5], v8[6], v8[7]};
    *(bf16x4*)&Kt[r * 68 + cc] = klo;
    *(bf16x4*)&Kt[r * 68 + cc + 4] = khi;
    *(bf16x4*)&Vt[r * 68 + cc] = vlo;
    *(bf16x4*)&Vt[r * 68 + cc + 4] = vhi;
  }
  __syncthreads();

  const f32x4 zero = {0.f, 0.f, 0.f, 0.f};
  f32x4 akv[4][4], a5[4];
#pragma unroll
  for (int i = 0; i < 4; ++i) {
    a5[i] = zero;
#pragma unroll
    for (int j = 0; j < 4; ++j) akv[i][j] = zero;
  }
  bf16x8 ones;
#pragma unroll
  for (int jj = 0; jj < 8; ++jj) ones[jj] = (bf16)1.0f;

#pragma unroll
  for (int c = 0; c < 2; ++c) {
    const int sw = wave * 64 + c * 32;
    bf16x8 av[4], bk[4];
#pragma unroll
    for (int jj = 0; jj < 8; ++jj) {
      const bf16* vr = &Vt[(sw + grp * 8 + jj) * 68];
      const bf16* kr = &Kt[(sw + grp * 8 + jj) * 68];
#pragma unroll
      for (int i = 0; i < 4; ++i) av[i][jj] = vr[i * 16 + mlane];
#pragma unroll
      for (int j = 0; j < 4; ++j) bk[j][jj] = kr[j * 16 + mlane];
    }
#pragma unroll
    for (int i = 0; i < 4; ++i)
#pragma unroll
      for (int j = 0; j < 4; ++j) akv[i][j] = MFMA(av[i], bk[j], akv[i][j]);
#pragma unroll
    for (int j = 0; j < 4; ++j) a5[j] = MFMA(ones, bk[j], a5[j]);
  }
  __syncthreads();  // done reading Kt/Vt; reuse smem for reduction

  float* Pr = (float*)smem;            // [4][4096]
  float* Kr = (float*)(smem + 65536);  // [4][64]
#pragma unroll
  for (int i = 0; i < 4; ++i)
#pragma unroll
    for (int j = 0; j < 4; ++j)
#pragma unroll
      for (int r = 0; r < 4; ++r)
        Pr[wave * 4096 + (i * 16 + grp * 4 + r) * 64 + j * 16 + mlane] =
            akv[i][j][r];
  if (grp == 0) {
#pragma unroll
    for (int j = 0; j < 4; ++j) Kr[wave * 64 + j * 16 + mlane] = a5[j][0];
  }
  __syncthreads();

  const int widx = bh * 32 + sch;
  float* pw = Pp + (size_t)widx * 4096;
  for (int o = tid; o < 4096; o += 256)
    pw[o] = Pr[o] + Pr[4096 + o] + Pr[8192 + o] + Pr[12288 + o];
  if (tid < 64)
    KsP[(size_t)widx * 64 + tid] =
        Kr[tid] + Kr[64 + tid] + Kr[128 + tid] + Kr[192 + tid];
}

// ----------------------------------------------------------------- reduce ---
__global__ __launch_bounds__(256) void reduce_kv2(
    const float* __restrict__ Pp, const float* __restrict__ KsP,
    bf16* __restrict__ kvb, bf16* __restrict__ ksb) {
  const int bh = blockIdx.x, y = blockIdx.y, tid = threadIdx.x;
  if (y < 16) {
    const int o = y * 256 + tid;
    const float* p = Pp + (size_t)bh * 32 * 4096 + o;
    float s = 0.f;
#pragma unroll
    for (int i = 0; i < 32; ++i) s += p[(size_t)i * 4096];
    kvb[(size_t)bh * 4096 + o] = (bf16)s;
  } else if (tid < 64) {
    const float* p = KsP + (size_t)bh * 32 * 64 + tid;
    float s = 0.f;
#pragma unroll
    for (int i = 0; i < 32; ++i) s += p[(size_t)i * 64];
    ksb[bh * 64 + tid] = (bf16)s;
  }
}

// ------------------------------------------------------------------- attn ---
// grid (bh=64, st=64): 128 q-rows per block, attn = (q@kv)/max(q.ksum,1e-6).
__global__ __launch_bounds__(256) void attn_k(
    const bf16* __restrict__ qb, const bf16* __restrict__ kvb,
    const bf16* __restrict__ ksb, bf16* __restrict__ attn) {
  const int bh = blockIdx.x, st = blockIdx.y;
  const int b = bh >> 4, h = bh & 15;
  const int tid = threadIdx.x, lane = tid & 63, wave = tid >> 6;
  const int grp = lane >> 4, mlane = lane & 15;
  const int s0 = st * 128, m0q = wave * 32;

  bf16x8 bkv[2][4], b5v[2];
#pragma unroll
  for (int kc = 0; kc < 2; ++kc) {
#pragma unroll
    for (int j = 0; j < 4; ++j)
      bkv[kc][j] = *(const bf16x8*)&kvb[(size_t)bh * 4096 +
                                        (j * 16 + mlane) * 64 + kc * 32 + grp * 8];
    b5v[kc] = *(const bf16x8*)&ksb[bh * 64 + kc * 32 + grp * 8];
  }

  bf16x8 aq[2][2];
#pragma unroll
  for (int kc = 0; kc < 2; ++kc)
#pragma unroll
    for (int i = 0; i < 2; ++i)
      aq[kc][i] = *(const bf16x8*)&qb[(size_t)(b * 8192 + s0 + m0q + i * 16 + mlane) * 1024 +
                                      h * 64 + kc * 32 + grp * 8];

  const f32x4 zero = {0.f, 0.f, 0.f, 0.f};
  f32x4 ao[2][4], a5[2];
#pragma unroll
  for (int i = 0; i < 2; ++i) {
    a5[i] = zero;
#pragma unroll
    for (int j = 0; j < 4; ++j) ao[i][j] = zero;
  }
#pragma unroll
  for (int kc = 0; kc < 2; ++kc)
#pragma unroll
    for (int i = 0; i < 2; ++i) {
#pragma unroll
      for (int j = 0; j < 4; ++j) ao[i][j] = MFMA(aq[kc][i], bkv[kc][j], ao[i][j]);
      a5[i] = MFMA(aq[kc][i], b5v[kc], a5[i]);
    }

#pragma unroll
  for (int i = 0; i < 2; ++i)
#pragma unroll
    for (int r = 0; r < 4; ++r) {
      const float inv = 1.0f / fmaxf(a5[i][r], 1e-6f);
      bf16* op = attn + (size_t)(b * 8192 + s0 + m0q + i * 16 + grp * 4 + r) * 1024 + h * 64;
#pragma unroll
      for (int j = 0; j < 4; ++j)
        op[j * 16 + mlane] = (bf16)(ao[i][j][r] * inv);
    }
}

// ----------------------------------------------------------------- launch ---
extern "C" void kernel_launch(void* const* d_in, const int* in_sizes, int n_in,
                              void* d_out, int out_size, void* d_ws, size_t ws_size,
                              hipStream_t stream) {
  const float* x     = (const float*)d_in[0];
  const float* w_qkv = (const float*)d_in[1];
  const float* w_out = (const float*)d_in[2];
  char* O  = (char*)d_out;
  char* A  = (char*)d_in[0];
  char* W1 = (char*)d_in[1];

  bf16*  xb   = (bf16*)O;                       // [32768][1024]
  bf16*  wbq  = (bf16*)(O + 67108864);          // [3072][1024]
  float* Pp   = (float*)(O + 75497472);         // [2048][4096]
  float* KsP  = (float*)(O + 109051904);        // [2048][64]
  bf16*  kb   = (bf16*)A;                       // [32768][1024]
  bf16*  vb   = (bf16*)(A + 67108864);          // [32768][1024]
  bf16*  qb   = (bf16*)A;                       // over kb (dead)
  bf16*  attn = (bf16*)(A + 67108864);          // over vb (dead)
  bf16*  wbo  = (bf16*)W1;                      // [1024][1024]
  bf16*  kvb  = (bf16*)(W1 + 2097152);          // [64][4096]
  bf16*  ksb  = (bf16*)(W1 + 2621440);          // [64][64]

  cvt_bf16<<<2048, 256, 0, stream>>>(x, xb, 4194304);
  cvt_bf16<<<1536, 256, 0, stream>>>(w_qkv, wbq, 393216);
  cvt_bf16<<<512, 256, 0, stream>>>(w_out, wbo, 131072);   // W1 f32 dead now
  // K/V projection: B-tiles fastest so the A-panel is reused by 16 blocks
  gemm_bf16o<<<dim3(16, 256), 256, 0, stream>>>(xb, wbq + (size_t)1024 * 1024,
                                                kb, vb, 8);
  fold_kv<<<dim3(64, 32), 256, 0, stream>>>(kb, vb, Pp, KsP);
  reduce_kv2<<<dim3(64, 17), 256, 0, stream>>>(Pp, KsP, kvb, ksb);
  gemm_bf16o<<<dim3(8, 256), 256, 0, stream>>>(xb, wbq, qb, qb, 8);
  attn_k<<<dim3(64, 64), 256, 0, stream>>>(qb, kvb, ksb, attn);
  gemm_f32o<<<dim3(8, 256), 256, 0, stream>>>(attn, wbo, (float*)O);
}

// Round 2
// 574.827 us; speedup vs baseline: 2.3584x; 1.2637x over previous
//
#include <hip/hip_runtime.h>
#include <cstdint>
#include <cstddef>

// FullLinearAttention — decomposed pipeline; GEMMs use the 256x256/BK=32
// ring-3 counted-vmcnt phase schedule (T2+T3+T4+T5 port, plain HIP).
//   K0  cvt:    xb=bf16(x) -> O[0,64M); wbq -> O[64M,70M); wbo -> W1[0,2M)
//   K1  kv GEMM: elu(x@Wk^T)->kb=A[0,64M), x@Wv^T->vb=A[64M,128M)
//   K2  fold:   partial kv/ksum -> Pp O[72M,104M), KsP O[104M,104.5M)
//   K3  reduce: -> kvb,ksb (bf16) in W1[2M,2.51M)
//   K4  q GEMM: qb=elu(x@Wq^T) -> A[0,64M)  (kb dead)
//   K5  attn:   (q@kv)/max(q.ksum,1e-6) -> attn bf16 A[64M,128M) (vb dead)
//   K6  out GEMM: attn@wbo^T -> f32 directly into d_out

typedef __bf16 bf16;
typedef __bf16 bf16x8 __attribute__((ext_vector_type(8)));
typedef __bf16 bf16x4 __attribute__((ext_vector_type(4)));
typedef float  f32x4  __attribute__((ext_vector_type(4)));

#define MFMA(a, b, c) __builtin_amdgcn_mfma_f32_16x16x32_bf16((a), (b), (c), 0, 0, 0)

__device__ __forceinline__ void gld_lds16(const bf16* g, bf16* l) {
  __builtin_amdgcn_global_load_lds(
      (const __attribute__((address_space(1))) void*)g,
      (__attribute__((address_space(3))) void*)l, 16, 0, 0);
}

// ---------------------------------------------------------------- convert ---
__global__ __launch_bounds__(256) void cvt_bf16(const float* __restrict__ src,
                                                bf16* __restrict__ dst, int n8) {
  const int stride = gridDim.x * 256;
  for (int i = blockIdx.x * 256 + threadIdx.x; i < n8; i += stride) {
    const float* p = src + (size_t)i * 8;
    f32x4 a = *(const f32x4*)p;
    f32x4 b = *(const f32x4*)(p + 4);
    bf16x8 r;
    r[0] = (bf16)a[0]; r[1] = (bf16)a[1]; r[2] = (bf16)a[2]; r[3] = (bf16)a[3];
    r[4] = (bf16)b[0]; r[5] = (bf16)b[1]; r[6] = (bf16)b[2]; r[7] = (bf16)b[3];
    *(bf16x8*)(dst + (size_t)i * 8) = r;
  }
}

// --------------------------------------------- pipelined GEMM (8-phase port)
// C[M,N] = A[M,1024] @ B[N,1024]^T, BM=BN=256, BK=32, ring-3 LDS dbuf.
// 8 waves: wm=w>>2 (2), wn=w&3 (4); per-wave 128x64 output (acc[8][4]).
// LDS granule swizzle c' = c ^ ((row>>1)&3) (16B granules, 4/row):
// realized via pre-swizzled global source + swizzled ds_read (linear dest).
// Counted vmcnt: stage tile t+2 during iter t; vmcnt(4) at iter top.
template<int F32OUT>
__global__ __launch_bounds__(512, 2) void gemm_pipe(
    const bf16* __restrict__ A, const bf16* __restrict__ B,
    bf16* __restrict__ out0, bf16* __restrict__ out1,
    float* __restrict__ outf, int NC, int nelu) {
  __shared__ __align__(16) bf16 sA[3][256 * 32];
  __shared__ __align__(16) bf16 sB[3][256 * 32];
  constexpr int NT = 32;  // K=1024 / BK=32
  const int tid = threadIdx.x;
  const int w = tid >> 6, lane = tid & 63;
  const int grp = lane >> 4, mlane = lane & 15;
  const int wm = w >> 2, wn = w & 3;

  // bijective XCD swizzle (gridDim.x % 8 == 0 for all our grids)
  int bid = (int)blockIdx.x;
  const int cpx = (int)gridDim.x >> 3;
  bid = (bid & 7) * cpx + (bid >> 3);
  const int rt = bid / NC, ct = bid - rt * NC;
  const int rowA0 = rt * 256, colB0 = ct * 256;

  // staging: lane covers granule G = i*512 + w*64 + lane of the [256][4]-granule
  // tile; row = G>>2, cG = G&3; source col-granule = cG ^ ((row>>1)&3).
  const int lr = w * 16 + (lane >> 2);                      // 0..127 (+128*i)
  const int lcs = (lane & 3) ^ ((lane >> 3) & 3);
  const bf16* pA = A + (size_t)(rowA0 + lr) * 1024 + lcs * 8;
  const bf16* pB = B + (size_t)(colB0 + lr) * 1024 + lcs * 8;
  const int dst = (w * 64 + lane) * 8;                      // elems; +4096 for i=1

  // ds_read swizzled granule offset (elems): rows are base16+mlane
  const int cgo = (grp ^ ((mlane >> 1) & 3)) * 8;
  const int arow = wm * 128 + mlane;
  const int brow = wn * 64 + mlane;

  f32x4 acc[8][4];
  const f32x4 zero = {0.f, 0.f, 0.f, 0.f};
#pragma unroll
  for (int i = 0; i < 8; ++i)
#pragma unroll
    for (int j = 0; j < 4; ++j) acc[i][j] = zero;

  // prologue: stage tiles 0 and 1 (4 loads each)
#pragma unroll
  for (int t = 0; t < 2; ++t) {
    const int kk = t * 32;
    bf16* a = &sA[t][0];
    bf16* b = &sB[t][0];
    gld_lds16(pA + kk, a + dst);
    gld_lds16(pB + kk, b + dst);
    gld_lds16(pA + kk + 131072, a + dst + 4096);
    gld_lds16(pB + kk + 131072, b + dst + 4096);
  }

  for (int t = 0; t < NT; ++t) {
    // top-of-iteration: tile t complete, tile t+1's 4 loads stay in flight
    if (t < NT - 1) asm volatile("s_waitcnt vmcnt(4)" ::: "memory");
    else            asm volatile("s_waitcnt vmcnt(0)" ::: "memory");
    __builtin_amdgcn_s_barrier();
    __builtin_amdgcn_sched_barrier(0);

    const int bi = t % 3;
    const bf16* a = &sA[bi][0];
    const bf16* b = &sB[bi][0];
    const int ni = (t + 2) % 3;
    bf16* na = &sA[ni][0];
    bf16* nb = &sB[ni][0];
    const int kk = (t + 2) * 32;
    const bool st = (t + 2) < NT;

    bf16x8 bv[4], af[4];
    // ---- phase 0: rows wm*128 + [0,64)
#pragma unroll
    for (int nf = 0; nf < 4; ++nf)
      bv[nf] = *(const bf16x8*)&b[(brow + nf * 16) * 32 + cgo];
#pragma unroll
    for (int i = 0; i < 4; ++i)
      af[i] = *(const bf16x8*)&a[(arow + i * 16) * 32 + cgo];
    if (st) { gld_lds16(pA + kk, na + dst); gld_lds16(pB + kk, nb + dst); }
    __builtin_amdgcn_s_barrier();
    asm volatile("s_waitcnt lgkmcnt(0)" ::: "memory");
    __builtin_amdgcn_sched_barrier(0);
    __builtin_amdgcn_s_setprio(1);
#pragma unroll
    for (int i = 0; i < 4; ++i)
#pragma unroll
      for (int nf = 0; nf < 4; ++nf)
        acc[i][nf] = MFMA(af[i], bv[nf], acc[i][nf]);
    __builtin_amdgcn_s_setprio(0);
    __builtin_amdgcn_s_barrier();

    // ---- phase 1: rows wm*128 + [64,128)
#pragma unroll
    for (int i = 0; i < 4; ++i)
      af[i] = *(const bf16x8*)&a[(arow + 64 + i * 16) * 32 + cgo];
    if (st) { gld_lds16(pA + kk + 131072, na + dst + 4096);
              gld_lds16(pB + kk + 131072, nb + dst + 4096); }
    __builtin_amdgcn_s_barrier();
    asm volatile("s_waitcnt lgkmcnt(0)" ::: "memory");
    __builtin_amdgcn_sched_barrier(0);
    __builtin_amdgcn_s_setprio(1);
#pragma unroll
    for (int i = 0; i < 4; ++i)
#pragma unroll
      for (int nf = 0; nf < 4; ++nf)
        acc[4 + i][nf] = MFMA(af[i], bv[nf], acc[4 + i][nf]);
    __builtin_amdgcn_s_setprio(0);
    __builtin_amdgcn_s_barrier();
  }

  // epilogue
  const int rbase = rowA0 + wm * 128 + grp * 4;
  const int cb0 = colB0 + wn * 64;
  if constexpr (F32OUT) {
#pragma unroll
    for (int mf = 0; mf < 8; ++mf)
#pragma unroll
      for (int nf = 0; nf < 4; ++nf) {
        float* cp = outf + (size_t)(rbase + mf * 16) * 1024 + cb0 + nf * 16 + mlane;
#pragma unroll
        for (int rr = 0; rr < 4; ++rr) cp[(size_t)rr * 1024] = acc[mf][nf][rr];
      }
  } else {
    const bool iselu = (ct < nelu);
    bf16* dp = iselu ? out0 : out1;
    const int cb = (iselu ? cb0 : cb0 - nelu * 256);
#pragma unroll
    for (int mf = 0; mf < 8; ++mf)
#pragma unroll
      for (int nf = 0; nf < 4; ++nf)
#pragma unroll
        for (int rr = 0; rr < 4; ++rr) {
          float v = acc[mf][nf][rr];
          if (iselu) v = (v > 0.f) ? (v + 1.f) : __expf(v);
          dp[(size_t)(rbase + mf * 16 + rr) * 1024 + cb + nf * 16 + mlane] = (bf16)v;
        }
  }
}

// ------------------------------------------------------------------- fold ---
__global__ __launch_bounds__(256) void fold_kv(
    const bf16* __restrict__ kb, const bf16* __restrict__ vb,
    float* __restrict__ Pp, float* __restrict__ KsP) {
  __shared__ __align__(16) char smem[69632];
  bf16* Kt = (bf16*)smem;            // [256][68]
  bf16* Vt = (bf16*)(smem + 34816);  // [256][68]
  const int bh = blockIdx.x, sch = blockIdx.y;
  const int b = bh >> 4, h = bh & 15;
  const int tid = threadIdx.x, lane = tid & 63, wave = tid >> 6;
  const int grp = lane >> 4, mlane = lane & 15;
  const int rr = tid >> 3, cc = (tid & 7) * 8;

#pragma unroll
  for (int p = 0; p < 8; ++p) {
    const int r = p * 32 + rr;
    const size_t go = (size_t)(b * 8192 + sch * 256 + r) * 1024 + h * 64 + cc;
    bf16x8 k8 = *(const bf16x8*)(kb + go);
    bf16x8 v8 = *(const bf16x8*)(vb + go);
    bf16x4 klo = {k8[0], k8[1], k8[2], k8[3]}, khi = {k8[4], k8[5], k8[6], k8[7]};
    bf16x4 vlo = {v8[0], v8[1], v8[2], v8[3]}, vhi = {v8[4], v8[5], v8[6], v8[7]};
    *(bf16x4*)&Kt[r * 68 + cc] = klo;
    *(bf16x4*)&Kt[r * 68 + cc + 4] = khi;
    *(bf16x4*)&Vt[r * 68 + cc] = vlo;
    *(bf16x4*)&Vt[r * 68 + cc + 4] = vhi;
  }
  __syncthreads();

  const f32x4 zero = {0.f, 0.f, 0.f, 0.f};
  f32x4 akv[4][4], a5[4];
#pragma unroll
  for (int i = 0; i < 4; ++i) {
    a5[i] = zero;
#pragma unroll
    for (int j = 0; j < 4; ++j) akv[i][j] = zero;
  }
  bf16x8 ones;
#pragma unroll
  for (int jj = 0; jj < 8; ++jj) ones[jj] = (bf16)1.0f;

#pragma unroll
  for (int c = 0; c < 2; ++c) {
    const int sw = wave * 64 + c * 32;
    bf16x8 av[4], bk[4];
#pragma unroll
    for (int jj = 0; jj < 8; ++jj) {
      const bf16* vr = &Vt[(sw + grp * 8 + jj) * 68];
      const bf16* kr = &Kt[(sw + grp * 8 + jj) * 68];
#pragma unroll
      for (int i = 0; i < 4; ++i) av[i][jj] = vr[i * 16 + mlane];
#pragma unroll
      for (int j = 0; j < 4; ++j) bk[j][jj] = kr[j * 16 + mlane];
    }
#pragma unroll
    for (int i = 0; i < 4; ++i)
#pragma unroll
      for (int j = 0; j < 4; ++j) akv[i][j] = MFMA(av[i], bk[j], akv[i][j]);
#pragma unroll
    for (int j = 0; j < 4; ++j) a5[j] = MFMA(ones, bk[j], a5[j]);
  }
  __syncthreads();

  float* Pr = (float*)smem;            // [4][4096]
  float* Kr = (float*)(smem + 65536);  // [4][64]
#pragma unroll
  for (int i = 0; i < 4; ++i)
#pragma unroll
    for (int j = 0; j < 4; ++j)
#pragma unroll
      for (int r = 0; r < 4; ++r)
        Pr[wave * 4096 + (i * 16 + grp * 4 + r) * 64 + j * 16 + mlane] =
            akv[i][j][r];
  if (grp == 0) {
#pragma unroll
    for (int j = 0; j < 4; ++j) Kr[wave * 64 + j * 16 + mlane] = a5[j][0];
  }
  __syncthreads();

  const int widx = bh * 32 + sch;
  float* pw = Pp + (size_t)widx * 4096;
  for (int o = tid; o < 4096; o += 256)
    pw[o] = Pr[o] + Pr[4096 + o] + Pr[8192 + o] + Pr[12288 + o];
  if (tid < 64)
    KsP[(size_t)widx * 64 + tid] =
        Kr[tid] + Kr[64 + tid] + Kr[128 + tid] + Kr[192 + tid];
}

// ----------------------------------------------------------------- reduce ---
__global__ __launch_bounds__(256) void reduce_kv2(
    const float* __restrict__ Pp, const float* __restrict__ KsP,
    bf16* __restrict__ kvb, bf16* __restrict__ ksb) {
  const int bh = blockIdx.x, y = blockIdx.y, tid = threadIdx.x;
  if (y < 16) {
    const int o = y * 256 + tid;
    const float* p = Pp + (size_t)bh * 32 * 4096 + o;
    float s = 0.f;
#pragma unroll
    for (int i = 0; i < 32; ++i) s += p[(size_t)i * 4096];
    kvb[(size_t)bh * 4096 + o] = (bf16)s;
  } else if (tid < 64) {
    const float* p = KsP + (size_t)bh * 32 * 64 + tid;
    float s = 0.f;
#pragma unroll
    for (int i = 0; i < 32; ++i) s += p[(size_t)i * 64];
    ksb[bh * 64 + tid] = (bf16)s;
  }
}

// ------------------------------------------------------------------- attn ---
__global__ __launch_bounds__(256) void attn_k(
    const bf16* __restrict__ qb, const bf16* __restrict__ kvb,
    const bf16* __restrict__ ksb, bf16* __restrict__ attn) {
  const int bh = blockIdx.x, st = blockIdx.y;
  const int b = bh >> 4, h = bh & 15;
  const int tid = threadIdx.x, lane = tid & 63, wave = tid >> 6;
  const int grp = lane >> 4, mlane = lane & 15;
  const int s0 = st * 128, m0q = wave * 32;

  bf16x8 bkv[2][4], b5v[2];
#pragma unroll
  for (int kc = 0; kc < 2; ++kc) {
#pragma unroll
    for (int j = 0; j < 4; ++j)
      bkv[kc][j] = *(const bf16x8*)&kvb[(size_t)bh * 4096 +
                                        (j * 16 + mlane) * 64 + kc * 32 + grp * 8];
    b5v[kc] = *(const bf16x8*)&ksb[bh * 64 + kc * 32 + grp * 8];
  }

  bf16x8 aq[2][2];
#pragma unroll
  for (int kc = 0; kc < 2; ++kc)
#pragma unroll
    for (int i = 0; i < 2; ++i)
      aq[kc][i] = *(const bf16x8*)&qb[(size_t)(b * 8192 + s0 + m0q + i * 16 + mlane) * 1024 +
                                      h * 64 + kc * 32 + grp * 8];

  const f32x4 zero = {0.f, 0.f, 0.f, 0.f};
  f32x4 ao[2][4], a5[2];
#pragma unroll
  for (int i = 0; i < 2; ++i) {
    a5[i] = zero;
#pragma unroll
    for (int j = 0; j < 4; ++j) ao[i][j] = zero;
  }
#pragma unroll
  for (int kc = 0; kc < 2; ++kc)
#pragma unroll
    for (int i = 0; i < 2; ++i) {
#pragma unroll
      for (int j = 0; j < 4; ++j) ao[i][j] = MFMA(aq[kc][i], bkv[kc][j], ao[i][j]);
      a5[i] = MFMA(aq[kc][i], b5v[kc], a5[i]);
    }

#pragma unroll
  for (int i = 0; i < 2; ++i)
#pragma unroll
    for (int r = 0; r < 4; ++r) {
      const float inv = 1.0f / fmaxf(a5[i][r], 1e-6f);
      bf16* op = attn + (size_t)(b * 8192 + s0 + m0q + i * 16 + grp * 4 + r) * 1024 + h * 64;
#pragma unroll
      for (int j = 0; j < 4; ++j)
        op[j * 16 + mlane] = (bf16)(ao[i][j][r] * inv);
    }
}

// ----------------------------------------------------------------- launch ---
extern "C" void kernel_launch(void* const* d_in, const int* in_sizes, int n_in,
                              void* d_out, int out_size, void* d_ws, size_t ws_size,
                              hipStream_t stream) {
  const float* x     = (const float*)d_in[0];
  const float* w_qkv = (const float*)d_in[1];
  const float* w_out = (const float*)d_in[2];
  char* O  = (char*)d_out;
  char* A  = (char*)d_in[0];
  char* W1 = (char*)d_in[1];

  bf16*  xb   = (bf16*)O;                       // [32768][1024]
  bf16*  wbq  = (bf16*)(O + 67108864);          // [3072][1024]
  float* Pp   = (float*)(O + 75497472);         // [2048][4096]
  float* KsP  = (float*)(O + 109051904);        // [2048][64]
  bf16*  kb   = (bf16*)A;                       // [32768][1024]
  bf16*  vb   = (bf16*)(A + 67108864);          // [32768][1024]
  bf16*  qb   = (bf16*)A;                       // over kb (dead)
  bf16*  attn = (bf16*)(A + 67108864);          // over vb (dead)
  bf16*  wbo  = (bf16*)W1;                      // [1024][1024]
  bf16*  kvb  = (bf16*)(W1 + 2097152);          // [64][4096]
  bf16*  ksb  = (bf16*)(W1 + 2621440);          // [64][64]

  cvt_bf16<<<2048, 256, 0, stream>>>(x, xb, 4194304);
  cvt_bf16<<<1536, 256, 0, stream>>>(w_qkv, wbq, 393216);
  cvt_bf16<<<512, 256, 0, stream>>>(w_out, wbo, 131072);
  // K/V projection: N=2048 (k|v), elu on first 4 col-tiles
  gemm_pipe<0><<<1024, 512, 0, stream>>>(xb, wbq + (size_t)1024 * 1024,
                                         kb, vb, nullptr, 8, 4);
  fold_kv<<<dim3(64, 32), 256, 0, stream>>>(kb, vb, Pp, KsP);
  reduce_kv2<<<dim3(64, 17), 256, 0, stream>>>(Pp, KsP, kvb, ksb);
  gemm_pipe<0><<<512, 512, 0, stream>>>(xb, wbq, qb, qb, nullptr, 4, 4);
  attn_k<<<dim3(64, 64), 256, 0, stream>>>(qb, kvb, ksb, attn);
  gemm_pipe<1><<<512, 512, 0, stream>>>(attn, wbo, nullptr, nullptr,
                                        (float*)O, 4, 0);
}

// Round 3
// 538.047 us; speedup vs baseline: 2.5196x; 1.0684x over previous
//
#include <hip/hip_runtime.h>
#include <cstdint>
#include <cstddef>

// FullLinearAttention — fused pipeline, 256x128/BK=32 ring-3 counted-vmcnt
// GEMM core, 4 waves/block, 72KB LDS -> 2 blocks/CU co-resident.
//   K0  cvt:     xb=bf16(x) -> O[0,64M); wbq -> O[64M,70M); wbo -> W1[0,2M)
//   K1  kvfold:  per (rt,h) block: [256 x (k64|v64)] GEMM tile, elu on k,
//                in-LDS fold -> Pp O[72M,104M) (2048x4096 f32) + KsP
//   K2  reduce:  32 row-tile partials -> kvb,ksb (bf16) in W1[2M,2.51M)
//   K3  qattn:   q GEMM tile (wave = one head), elu, LDS round-trip,
//                (q@kv)/max(q.ksum,1e-6) -> attn bf16 A[0,64M)
//   K4  out:     attn@wbo^T -> f32 directly into d_out O[0,128M)

typedef __bf16 bf16;
typedef __bf16 bf16x8 __attribute__((ext_vector_type(8)));
typedef float  f32x4  __attribute__((ext_vector_type(4)));

#define MFMA(a, b, c) __builtin_amdgcn_mfma_f32_16x16x32_bf16((a), (b), (c), 0, 0, 0)

__device__ __forceinline__ void gld_lds16(const bf16* g, bf16* l) {
  __builtin_amdgcn_global_load_lds(
      (const __attribute__((address_space(1))) void*)g,
      (__attribute__((address_space(3))) void*)l, 16, 0, 0);
}

// ---------------------------------------------------------------- convert ---
__global__ __launch_bounds__(256) void cvt_bf16(const float* __restrict__ src,
                                                bf16* __restrict__ dst, int n8) {
  const int stride = gridDim.x * 256;
  for (int i = blockIdx.x * 256 + threadIdx.x; i < n8; i += stride) {
    const float* p = src + (size_t)i * 8;
    f32x4 a = *(const f32x4*)p;
    f32x4 b = *(const f32x4*)(p + 4);
    bf16x8 r;
    r[0] = (bf16)a[0]; r[1] = (bf16)a[1]; r[2] = (bf16)a[2]; r[3] = (bf16)a[3];
    r[4] = (bf16)b[0]; r[5] = (bf16)b[1]; r[6] = (bf16)b[2]; r[7] = (bf16)b[3];
    *(bf16x8*)(dst + (size_t)i * 8) = r;
  }
}

// --------------------------------------------------------- shared K-loop ----
// C[256,128] += A[256rows,1024] @ B[128rows,1024]^T.  BK=32, ring-3 slabs of
// 12288 elems (A 8192 | B 4096) in smem[36864].  4 waves: wm=w>>1 (128 rows),
// wn=w&1 (64 cols).  Granule swizzle col^=(row>>1)&3 via pre-swizzled source.
// Counted vmcnt: 6 loads/tile, stage t+2 during t, vmcnt(6) at iter top.
__device__ __forceinline__ void kloop(
    bf16* smem, const bf16* pA, const bf16* pB0, const bf16* pB1,
    int tid, int arow, int brow, int cgo, f32x4 (&acc)[8][4]) {
  constexpr int NT = 32;
  const int dstA = tid * 8, dstB = 8192 + tid * 8;
#pragma unroll
  for (int t = 0; t < 2; ++t) {
    bf16* s = smem + t * 12288;
    const int kk = t * 32;
    gld_lds16(pA + kk,          s + dstA);
    gld_lds16(pA + kk + 65536,  s + dstA + 2048);
    gld_lds16(pA + kk + 131072, s + dstA + 4096);
    gld_lds16(pA + kk + 196608, s + dstA + 6144);
    gld_lds16(pB0 + kk,         s + dstB);
    gld_lds16(pB1 + kk,         s + dstB + 2048);
  }
  for (int t = 0; t < NT; ++t) {
    if (t < NT - 1) asm volatile("s_waitcnt vmcnt(6)" ::: "memory");
    else            asm volatile("s_waitcnt vmcnt(0)" ::: "memory");
    __builtin_amdgcn_s_barrier();
    __builtin_amdgcn_sched_barrier(0);

    bf16* s  = smem + (t % 3) * 12288;
    bf16* ns = smem + ((t + 2) % 3) * 12288;
    const int kk = (t + 2) * 32;
    const bool st = (t + 2) < NT;

    bf16x8 bv[4], af[4];
#pragma unroll
    for (int nf = 0; nf < 4; ++nf)
      bv[nf] = *(const bf16x8*)&s[8192 + (brow + nf * 16) * 32 + cgo];
#pragma unroll
    for (int i = 0; i < 4; ++i)
      af[i] = *(const bf16x8*)&s[(arow + i * 16) * 32 + cgo];
    if (st) {
      gld_lds16(pA + kk,         ns + dstA);
      gld_lds16(pA + kk + 65536, ns + dstA + 2048);
      gld_lds16(pB0 + kk,        ns + dstB);
    }
    __builtin_amdgcn_s_barrier();
    asm volatile("s_waitcnt lgkmcnt(0)" ::: "memory");
    __builtin_amdgcn_sched_barrier(0);
    __builtin_amdgcn_s_setprio(1);
#pragma unroll
    for (int i = 0; i < 4; ++i)
#pragma unroll
      for (int nf = 0; nf < 4; ++nf)
        acc[i][nf] = MFMA(af[i], bv[nf], acc[i][nf]);
    __builtin_amdgcn_s_setprio(0);
    __builtin_amdgcn_s_barrier();

#pragma unroll
    for (int i = 0; i < 4; ++i)
      af[i] = *(const bf16x8*)&s[(arow + 64 + i * 16) * 32 + cgo];
    if (st) {
      gld_lds16(pA + kk + 131072, ns + dstA + 4096);
      gld_lds16(pA + kk + 196608, ns + dstA + 6144);
      gld_lds16(pB1 + kk,         ns + dstB + 2048);
    }
    __builtin_amdgcn_s_barrier();
    asm volatile("s_waitcnt lgkmcnt(0)" ::: "memory");
    __builtin_amdgcn_sched_barrier(0);
    __builtin_amdgcn_s_setprio(1);
#pragma unroll
    for (int i = 0; i < 4; ++i)
#pragma unroll
      for (int nf = 0; nf < 4; ++nf)
        acc[4 + i][nf] = MFMA(af[i], bv[nf], acc[4 + i][nf]);
    __builtin_amdgcn_s_setprio(0);
    __builtin_amdgcn_s_barrier();
  }
}

// ---------------------------------------------------------------- kvfold ----
// grid 2048 = 128 rt x 16 h (h fastest). Tile cols = head h's k (0..63, elu)
// and v (64..127). Fold epilogue -> one 64x64 f32 partial per block.
__global__ __launch_bounds__(256, 2) void gemm_kvfold(
    const bf16* __restrict__ xb, const bf16* __restrict__ wbq,
    float* __restrict__ Pp, float* __restrict__ KsP) {
  __shared__ __align__(16) bf16 smem[36864];
  const int tid = threadIdx.x;
  const int w = tid >> 6, lane = tid & 63;
  const int grp = lane >> 4, mlane = lane & 15;
  const int wm = w >> 1, wn = w & 1;

  int bid = (int)blockIdx.x;
  const int cpx = (int)gridDim.x >> 3;
  bid = (bid & 7) * cpx + (bid >> 3);
  const int h = bid & 15, rt = bid >> 4;
  const int rowA0 = rt * 256;

  const int lrr = tid >> 2;
  const int lcs = (tid & 3) ^ ((tid >> 3) & 3);
  const bf16* pA  = xb + (size_t)(rowA0 + lrr) * 1024 + lcs * 8;
  const bf16* pB0 = wbq + (size_t)(1024 + h * 64 + lrr) * 1024 + lcs * 8;
  const bf16* pB1 = wbq + (size_t)(2048 + h * 64 + lrr) * 1024 + lcs * 8;
  const int cgo = (grp ^ ((mlane >> 1) & 3)) * 8;
  const int arow = wm * 128 + mlane;
  const int brow = wn * 64 + mlane;

  const f32x4 zero = {0.f, 0.f, 0.f, 0.f};
  f32x4 acc[8][4];
#pragma unroll
  for (int i = 0; i < 8; ++i)
#pragma unroll
    for (int j = 0; j < 4; ++j) acc[i][j] = zero;

  kloop(smem, pA, pB0, pB1, tid, arow, brow, cgo, acc);

  // stage elu(k)|v into Kt/Vt [256][68] (2-way max on frag reads)
  bf16* Kt = smem;
  bf16* Vt = smem + 17408;
  {
    bf16* T = wn ? Vt : Kt;
#pragma unroll
    for (int mf = 0; mf < 8; ++mf)
#pragma unroll
      for (int nf = 0; nf < 4; ++nf)
#pragma unroll
        for (int r = 0; r < 4; ++r) {
          float v = acc[mf][nf][r];
          if (wn == 0) v = (v > 0.f) ? (v + 1.f) : __expf(v);
          T[(wm * 128 + mf * 16 + grp * 4 + r) * 68 + nf * 16 + mlane] = (bf16)v;
        }
  }
  __syncthreads();

  f32x4 akv[4][4], a5[4];
#pragma unroll
  for (int i = 0; i < 4; ++i) {
    a5[i] = zero;
#pragma unroll
    for (int j = 0; j < 4; ++j) akv[i][j] = zero;
  }
  bf16x8 ones;
#pragma unroll
  for (int jj = 0; jj < 8; ++jj) ones[jj] = (bf16)1.0f;

#pragma unroll
  for (int c = 0; c < 2; ++c) {
    const int sw = w * 64 + c * 32;
    bf16x8 av[4], bk[4];
#pragma unroll
    for (int jj = 0; jj < 8; ++jj) {
      const bf16* vr = &Vt[(sw + grp * 8 + jj) * 68];
      const bf16* kr = &Kt[(sw + grp * 8 + jj) * 68];
#pragma unroll
      for (int i = 0; i < 4; ++i) av[i][jj] = vr[i * 16 + mlane];
#pragma unroll
      for (int j = 0; j < 4; ++j) bk[j][jj] = kr[j * 16 + mlane];
    }
#pragma unroll
    for (int i = 0; i < 4; ++i)
#pragma unroll
      for (int j = 0; j < 4; ++j) akv[i][j] = MFMA(av[i], bk[j], akv[i][j]);
#pragma unroll
    for (int j = 0; j < 4; ++j) a5[j] = MFMA(ones, bk[j], a5[j]);
  }
  __syncthreads();

  // 4-wave tree reduce in LDS (Kt/Vt dead)
  float* Pr = (float*)smem;        // [2][4096]
  float* Kr = Pr + 8192;           // [2][64]
  if (w >= 2) {
#pragma unroll
    for (int i = 0; i < 4; ++i)
#pragma unroll
      for (int j = 0; j < 4; ++j)
#pragma unroll
        for (int r = 0; r < 4; ++r)
          Pr[(w - 2) * 4096 + (i * 16 + grp * 4 + r) * 64 + j * 16 + mlane] =
              akv[i][j][r];
    if (grp == 0) {
#pragma unroll
      for (int j = 0; j < 4; ++j) Kr[(w - 2) * 64 + j * 16 + mlane] = a5[j][0];
    }
  }
  __syncthreads();
  if (w < 2) {
#pragma unroll
    for (int i = 0; i < 4; ++i)
#pragma unroll
      for (int j = 0; j < 4; ++j)
#pragma unroll
        for (int r = 0; r < 4; ++r)
          akv[i][j][r] += Pr[w * 4096 + (i * 16 + grp * 4 + r) * 64 + j * 16 + mlane];
    if (grp == 0) {
#pragma unroll
      for (int j = 0; j < 4; ++j) a5[j][0] += Kr[w * 64 + j * 16 + mlane];
    }
  }
  __syncthreads();
  if (w == 1) {
#pragma unroll
    for (int i = 0; i < 4; ++i)
#pragma unroll
      for (int j = 0; j < 4; ++j)
#pragma unroll
        for (int r = 0; r < 4; ++r)
          Pr[(i * 16 + grp * 4 + r) * 64 + j * 16 + mlane] = akv[i][j][r];
    if (grp == 0) {
#pragma unroll
      for (int j = 0; j < 4; ++j) Kr[j * 16 + mlane] = a5[j][0];
    }
  }
  __syncthreads();
  if (w == 0) {
    const int widx = rt * 16 + h;
    float* pw = Pp + (size_t)widx * 4096;
#pragma unroll
    for (int i = 0; i < 4; ++i)
#pragma unroll
      for (int j = 0; j < 4; ++j)
#pragma unroll
        for (int r = 0; r < 4; ++r)
          pw[(i * 16 + grp * 4 + r) * 64 + j * 16 + mlane] =
              akv[i][j][r] + Pr[(i * 16 + grp * 4 + r) * 64 + j * 16 + mlane];
    if (grp == 0) {
#pragma unroll
      for (int j = 0; j < 4; ++j)
        KsP[(size_t)widx * 64 + j * 16 + mlane] =
            a5[j][0] + Kr[j * 16 + mlane];
    }
  }
}

// ----------------------------------------------------------------- reduce ---
__global__ __launch_bounds__(256) void reduce_kv2(
    const float* __restrict__ Pp, const float* __restrict__ KsP,
    bf16* __restrict__ kvb, bf16* __restrict__ ksb) {
  const int bh = blockIdx.x, y = blockIdx.y, tid = threadIdx.x;
  const int b = bh >> 4, h = bh & 15;
  if (y < 16) {
    const int o = y * 256 + tid;
    float s = 0.f;
#pragma unroll
    for (int i = 0; i < 32; ++i)
      s += Pp[(size_t)((b * 32 + i) * 16 + h) * 4096 + o];
    kvb[(size_t)bh * 4096 + o] = (bf16)s;
  } else if (tid < 64) {
    float s = 0.f;
#pragma unroll
    for (int i = 0; i < 32; ++i)
      s += KsP[(size_t)((b * 32 + i) * 16 + h) * 64 + tid];
    ksb[bh * 64 + tid] = (bf16)s;
  }
}

// ----------------------------------------------------------------- qattn ----
// grid 1024 = 128 rt x 8 ct (ct fastest). Wave = one head (head = ct*2+wn).
// Epilogue: elu->bf16->Qs (XOR-swizzled [64][64])->q@kv + normalizer -> attn.
__global__ __launch_bounds__(256, 2) void gemm_qattn(
    const bf16* __restrict__ xb, const bf16* __restrict__ wbq,
    const bf16* __restrict__ kvb, const bf16* __restrict__ ksb,
    bf16* __restrict__ attn) {
  __shared__ __align__(16) bf16 smem[36864];
  const int tid = threadIdx.x;
  const int w = tid >> 6, lane = tid & 63;
  const int grp = lane >> 4, mlane = lane & 15;
  const int wm = w >> 1, wn = w & 1;

  int bid = (int)blockIdx.x;
  const int cpx = (int)gridDim.x >> 3;
  bid = (bid & 7) * cpx + (bid >> 3);
  const int ct = bid & 7, rt = bid >> 3;
  const int rowA0 = rt * 256;

  const int lrr = tid >> 2;
  const int lcs = (tid & 3) ^ ((tid >> 3) & 3);
  const bf16* pA  = xb + (size_t)(rowA0 + lrr) * 1024 + lcs * 8;
  const bf16* pB0 = wbq + (size_t)(ct * 128 + lrr) * 1024 + lcs * 8;
  const bf16* pB1 = pB0 + (size_t)64 * 1024;
  const int cgo = (grp ^ ((mlane >> 1) & 3)) * 8;
  const int arow = wm * 128 + mlane;
  const int brow = wn * 64 + mlane;

  const f32x4 zero = {0.f, 0.f, 0.f, 0.f};
  f32x4 acc[8][4];
#pragma unroll
  for (int i = 0; i < 8; ++i)
#pragma unroll
    for (int j = 0; j < 4; ++j) acc[i][j] = zero;

  kloop(smem, pA, pB0, pB1, tid, arow, brow, cgo, acc);

  // per-head kv / ksum fragments (tiny, L2-hot)
  const int head = ct * 2 + wn;
  const int bh = (rt >> 5) * 16 + head;
  bf16x8 bkv[2][4], b5v[2];
#pragma unroll
  for (int ks = 0; ks < 2; ++ks) {
#pragma unroll
    for (int nf = 0; nf < 4; ++nf)
      bkv[ks][nf] = *(const bf16x8*)&kvb[(size_t)bh * 4096 +
                                         (nf * 16 + mlane) * 64 + ks * 32 + grp * 8];
    b5v[ks] = *(const bf16x8*)&ksb[bh * 64 + ks * 32 + grp * 8];
  }

  // wave-private Qs [64][64] with 3-bit granule XOR swizzle (stride 128B)
  bf16* Qs = smem + w * 4096;
  const int swr = (mlane >> 1) & 7;  // read-side swizzle (row = i*16+mlane)
#pragma unroll
  for (int mh = 0; mh < 2; ++mh) {
#pragma unroll
    for (int i = 0; i < 4; ++i)
#pragma unroll
      for (int nf = 0; nf < 4; ++nf)
#pragma unroll
        for (int r = 0; r < 4; ++r) {
          float v = acc[mh * 4 + i][nf][r];
          v = (v > 0.f) ? (v + 1.f) : __expf(v);
          const int rw = i * 16 + grp * 4 + r;
          const int d = nf * 16 + mlane;
          Qs[rw * 64 + (((d >> 3) ^ ((rw >> 1) & 7)) << 3) + (d & 7)] = (bf16)v;
        }
    bf16x8 aq2[4][2];
#pragma unroll
    for (int i = 0; i < 4; ++i)
#pragma unroll
      for (int ks = 0; ks < 2; ++ks)
        aq2[i][ks] = *(const bf16x8*)&Qs[(i * 16 + mlane) * 64 +
                                         (((ks * 4 + grp) ^ swr) << 3)];
    f32x4 ao[4][4], a5q[4];
#pragma unroll
    for (int i = 0; i < 4; ++i) {
      a5q[i] = zero;
#pragma unroll
      for (int nf = 0; nf < 4; ++nf) ao[i][nf] = zero;
    }
#pragma unroll
    for (int ks = 0; ks < 2; ++ks)
#pragma unroll
      for (int i = 0; i < 4; ++i) {
#pragma unroll
        for (int nf = 0; nf < 4; ++nf)
          ao[i][nf] = MFMA(aq2[i][ks], bkv[ks][nf], ao[i][nf]);
        a5q[i] = MFMA(aq2[i][ks], b5v[ks], a5q[i]);
      }
#pragma unroll
    for (int i = 0; i < 4; ++i)
#pragma unroll
      for (int r = 0; r < 4; ++r) {
        const float inv = 1.0f / fmaxf(a5q[i][r], 1e-6f);
        bf16* op = attn + (size_t)(rowA0 + wm * 128 + mh * 64 + i * 16 +
                                   grp * 4 + r) * 1024 + head * 64;
#pragma unroll
        for (int nf = 0; nf < 4; ++nf)
          op[nf * 16 + mlane] = (bf16)(ao[i][nf][r] * inv);
      }
  }
}

// ------------------------------------------------------------------- out ----
// grid 1024 = 128 rt x 8 ct. C f32 directly into d_out.
__global__ __launch_bounds__(256, 2) void gemm_out(
    const bf16* __restrict__ attn, const bf16* __restrict__ wbo,
    float* __restrict__ C) {
  __shared__ __align__(16) bf16 smem[36864];
  const int tid = threadIdx.x;
  const int w = tid >> 6, lane = tid & 63;
  const int grp = lane >> 4, mlane = lane & 15;
  const int wm = w >> 1, wn = w & 1;

  int bid = (int)blockIdx.x;
  const int cpx = (int)gridDim.x >> 3;
  bid = (bid & 7) * cpx + (bid >> 3);
  const int ct = bid & 7, rt = bid >> 3;
  const int rowA0 = rt * 256;

  const int lrr = tid >> 2;
  const int lcs = (tid & 3) ^ ((tid >> 3) & 3);
  const bf16* pA  = attn + (size_t)(rowA0 + lrr) * 1024 + lcs * 8;
  const bf16* pB0 = wbo + (size_t)(ct * 128 + lrr) * 1024 + lcs * 8;
  const bf16* pB1 = pB0 + (size_t)64 * 1024;
  const int cgo = (grp ^ ((mlane >> 1) & 3)) * 8;
  const int arow = wm * 128 + mlane;
  const int brow = wn * 64 + mlane;

  const f32x4 zero = {0.f, 0.f, 0.f, 0.f};
  f32x4 acc[8][4];
#pragma unroll
  for (int i = 0; i < 8; ++i)
#pragma unroll
    for (int j = 0; j < 4; ++j) acc[i][j] = zero;

  kloop(smem, pA, pB0, pB1, tid, arow, brow, cgo, acc);

#pragma unroll
  for (int mf = 0; mf < 8; ++mf)
#pragma unroll
    for (int nf = 0; nf < 4; ++nf) {
      float* cp = C + (size_t)(rowA0 + wm * 128 + mf * 16 + grp * 4) * 1024 +
                  ct * 128 + wn * 64 + nf * 16 + mlane;
#pragma unroll
      for (int r = 0; r < 4; ++r) cp[(size_t)r * 1024] = acc[mf][nf][r];
    }
}

// ----------------------------------------------------------------- launch ---
extern "C" void kernel_launch(void* const* d_in, const int* in_sizes, int n_in,
                              void* d_out, int out_size, void* d_ws, size_t ws_size,
                              hipStream_t stream) {
  const float* x     = (const float*)d_in[0];
  const float* w_qkv = (const float*)d_in[1];
  const float* w_out = (const float*)d_in[2];
  char* O  = (char*)d_out;
  char* A  = (char*)d_in[0];
  char* W1 = (char*)d_in[1];

  bf16*  xb   = (bf16*)O;                       // [32768][1024]
  bf16*  wbq  = (bf16*)(O + 67108864);          // [3072][1024]
  float* Pp   = (float*)(O + 75497472);         // [2048][4096] f32
  float* KsP  = (float*)(O + 109051904);        // [2048][64] f32
  bf16*  attn = (bf16*)A;                       // over x (dead after cvt)
  bf16*  wbo  = (bf16*)W1;                      // [1024][1024]
  bf16*  kvb  = (bf16*)(W1 + 2097152);          // [64][4096]
  bf16*  ksb  = (bf16*)(W1 + 2621440);          // [64][64]

  cvt_bf16<<<2048, 256, 0, stream>>>(x, xb, 4194304);
  cvt_bf16<<<1536, 256, 0, stream>>>(w_qkv, wbq, 393216);
  cvt_bf16<<<512, 256, 0, stream>>>(w_out, wbo, 131072);
  gemm_kvfold<<<2048, 256, 0, stream>>>(xb, wbq, Pp, KsP);
  reduce_kv2<<<dim3(64, 17), 256, 0, stream>>>(Pp, KsP, kvb, ksb);
  gemm_qattn<<<1024, 256, 0, stream>>>(xb, wbq, kvb, ksb, attn);
  gemm_out<<<1024, 256, 0, stream>>>(attn, wbo, (float*)O);
}

// Round 4
// 535.320 us; speedup vs baseline: 2.5325x; 1.0051x over previous
//
#include <hip/hip_runtime.h>
#include <cstdint>
#include <cstddef>

// FullLinearAttention — fused pipeline, 256x128/BK=32 ring-3 counted-vmcnt
// GEMM core, 4 waves/block, 72KB LDS -> 2 blocks/CU co-resident.
// R4: K-loop fully unrolled with compile-time ring-slab indices -> all
// ds_read/global_load_lds addresses become base+immediate (VALU removal).
//   K0  cvt:     xb=bf16(x) -> O[0,64M); wbq -> O[64M,70M); wbo -> W1[0,2M)
//   K1  kvfold:  per (rt,h) block: [256 x (k64|v64)] GEMM tile, elu on k,
//                in-LDS fold -> Pp O[72M,104M) (2048x4096 f32) + KsP
//   K2  reduce:  32 row-tile partials -> kvb,ksb (bf16) in W1[2M,2.51M)
//   K3  qattn:   q GEMM tile (wave = one head), elu, LDS round-trip,
//                (q@kv)/max(q.ksum,1e-6) -> attn bf16 A[0,64M)
//   K4  out:     attn@wbo^T -> f32 directly into d_out O[0,128M)

typedef __bf16 bf16;
typedef __bf16 bf16x8 __attribute__((ext_vector_type(8)));
typedef float  f32x4  __attribute__((ext_vector_type(4)));

#define MFMA(a, b, c) __builtin_amdgcn_mfma_f32_16x16x32_bf16((a), (b), (c), 0, 0, 0)

__device__ __forceinline__ void gld_lds16(const bf16* g, bf16* l) {
  __builtin_amdgcn_global_load_lds(
      (const __attribute__((address_space(1))) void*)g,
      (__attribute__((address_space(3))) void*)l, 16, 0, 0);
}

// ---------------------------------------------------------------- convert ---
__global__ __launch_bounds__(256) void cvt_bf16(const float* __restrict__ src,
                                                bf16* __restrict__ dst, int n8) {
  const int stride = gridDim.x * 256;
  for (int i = blockIdx.x * 256 + threadIdx.x; i < n8; i += stride) {
    const float* p = src + (size_t)i * 8;
    f32x4 a = *(const f32x4*)p;
    f32x4 b = *(const f32x4*)(p + 4);
    bf16x8 r;
    r[0] = (bf16)a[0]; r[1] = (bf16)a[1]; r[2] = (bf16)a[2]; r[3] = (bf16)a[3];
    r[4] = (bf16)b[0]; r[5] = (bf16)b[1]; r[6] = (bf16)b[2]; r[7] = (bf16)b[3];
    *(bf16x8*)(dst + (size_t)i * 8) = r;
  }
}

// --------------------------------------------------------- shared K-loop ----
// C[256,128] += A[256rows,1024] @ B[128rows,1024]^T.  BK=32, ring-3 slabs of
// 12288 elems (A 8192 | B 4096) in smem[36864].  4 waves: wm=w>>1 (128 rows),
// wn=w&1 (64 cols).  Granule swizzle col^=(row>>1)&3 via pre-swizzled source.
// Counted vmcnt: 6 loads/tile, stage t+2 during t, vmcnt(6) at iter top.
// SLAB = ring slot of the tile being computed (compile-time); stages into
// (SLAB+2)%3. gA/gB* already point at tile t+2's K-offset.
template<int SLAB, bool ST, bool LAST>
__device__ __forceinline__ void ktile(
    const bf16* vA, const bf16* vB, bf16* sA, bf16* sB,
    const bf16* gA, const bf16* gB0, const bf16* gB1,
    f32x4 (&acc)[8][4]) {
  constexpr int NS = (SLAB + 2) % 3;
  constexpr int CB = SLAB * 12288;
  if (!LAST) asm volatile("s_waitcnt vmcnt(6)" ::: "memory");
  else       asm volatile("s_waitcnt vmcnt(0)" ::: "memory");
  __builtin_amdgcn_s_barrier();
  __builtin_amdgcn_sched_barrier(0);

  bf16x8 bv[4], af[4];
#pragma unroll
  for (int nf = 0; nf < 4; ++nf)
    bv[nf] = *(const bf16x8*)&vB[CB + nf * 512];
#pragma unroll
  for (int i = 0; i < 4; ++i)
    af[i] = *(const bf16x8*)&vA[CB + i * 512];
  if (ST) {
    gld_lds16(gA,         sA + NS * 12288);
    gld_lds16(gA + 65536, sA + NS * 12288 + 2048);
    gld_lds16(gB0,        sB + NS * 12288);
  }
  __builtin_amdgcn_s_barrier();
  asm volatile("s_waitcnt lgkmcnt(0)" ::: "memory");
  __builtin_amdgcn_sched_barrier(0);
  __builtin_amdgcn_s_setprio(1);
#pragma unroll
  for (int i = 0; i < 4; ++i)
#pragma unroll
    for (int nf = 0; nf < 4; ++nf)
      acc[i][nf] = MFMA(af[i], bv[nf], acc[i][nf]);
  __builtin_amdgcn_s_setprio(0);
  __builtin_amdgcn_s_barrier();

#pragma unroll
  for (int i = 0; i < 4; ++i)
    af[i] = *(const bf16x8*)&vA[CB + 2048 + i * 512];
  if (ST) {
    gld_lds16(gA + 131072, sA + NS * 12288 + 4096);
    gld_lds16(gA + 196608, sA + NS * 12288 + 6144);
    gld_lds16(gB1,         sB + NS * 12288 + 2048);
  }
  __builtin_amdgcn_s_barrier();
  asm volatile("s_waitcnt lgkmcnt(0)" ::: "memory");
  __builtin_amdgcn_sched_barrier(0);
  __builtin_amdgcn_s_setprio(1);
#pragma unroll
  for (int i = 0; i < 4; ++i)
#pragma unroll
    for (int nf = 0; nf < 4; ++nf)
      acc[4 + i][nf] = MFMA(af[i], bv[nf], acc[4 + i][nf]);
  __builtin_amdgcn_s_setprio(0);
  __builtin_amdgcn_s_barrier();
}

__device__ __forceinline__ void kloop(
    bf16* smem, const bf16* pA, const bf16* pB0, const bf16* pB1,
    int tid, int arow, int brow, int cgo, f32x4 (&acc)[8][4]) {
  bf16* sA = smem + tid * 8;
  bf16* sB = smem + 8192 + tid * 8;
  // prologue: stage tiles 0,1 into slabs 0,1
#pragma unroll
  for (int t = 0; t < 2; ++t) {
    const int kk = t * 32;
    gld_lds16(pA + kk,          sA + t * 12288);
    gld_lds16(pA + kk + 65536,  sA + t * 12288 + 2048);
    gld_lds16(pA + kk + 131072, sA + t * 12288 + 4096);
    gld_lds16(pA + kk + 196608, sA + t * 12288 + 6144);
    gld_lds16(pB0 + kk,         sB + t * 12288);
    gld_lds16(pB1 + kk,         sB + t * 12288 + 2048);
  }
  const bf16* vA = smem + arow * 32 + cgo;
  const bf16* vB = smem + 8192 + brow * 32 + cgo;
  // fully unrolled: t=0..29 compute+stage(t+2); t=30,31 drain.
#pragma unroll
  for (int c = 0; c < 10; ++c) {
    const int o = 64 + c * 96;  // compile-time K-elem offset of tile 3c+2
    ktile<0, true, false>(vA, vB, sA, sB, pA + o,      pB0 + o,      pB1 + o,      acc);
    ktile<1, true, false>(vA, vB, sA, sB, pA + o + 32, pB0 + o + 32, pB1 + o + 32, acc);
    ktile<2, true, false>(vA, vB, sA, sB, pA + o + 64, pB0 + o + 64, pB1 + o + 64, acc);
  }
  ktile<0, false, false>(vA, vB, sA, sB, pA, pB0, pB1, acc);
  ktile<1, false, true >(vA, vB, sA, sB, pA, pB0, pB1, acc);
}

// ---------------------------------------------------------------- kvfold ----
// grid 2048 = 128 rt x 16 h (h fastest). Tile cols = head h's k (0..63, elu)
// and v (64..127). Fold epilogue -> one 64x64 f32 partial per block.
__global__ __launch_bounds__(256, 2) void gemm_kvfold(
    const bf16* __restrict__ xb, const bf16* __restrict__ wbq,
    float* __restrict__ Pp, float* __restrict__ KsP) {
  __shared__ __align__(16) bf16 smem[36864];
  const int tid = threadIdx.x;
  const int w = tid >> 6, lane = tid & 63;
  const int grp = lane >> 4, mlane = lane & 15;
  const int wm = w >> 1, wn = w & 1;

  int bid = (int)blockIdx.x;
  const int cpx = (int)gridDim.x >> 3;
  bid = (bid & 7) * cpx + (bid >> 3);
  const int h = bid & 15, rt = bid >> 4;
  const int rowA0 = rt * 256;

  const int lrr = tid >> 2;
  const int lcs = (tid & 3) ^ ((tid >> 3) & 3);
  const bf16* pA  = xb + (size_t)(rowA0 + lrr) * 1024 + lcs * 8;
  const bf16* pB0 = wbq + (size_t)(1024 + h * 64 + lrr) * 1024 + lcs * 8;
  const bf16* pB1 = wbq + (size_t)(2048 + h * 64 + lrr) * 1024 + lcs * 8;
  const int cgo = (grp ^ ((mlane >> 1) & 3)) * 8;
  const int arow = wm * 128 + mlane;
  const int brow = wn * 64 + mlane;

  const f32x4 zero = {0.f, 0.f, 0.f, 0.f};
  f32x4 acc[8][4];
#pragma unroll
  for (int i = 0; i < 8; ++i)
#pragma unroll
    for (int j = 0; j < 4; ++j) acc[i][j] = zero;

  kloop(smem, pA, pB0, pB1, tid, arow, brow, cgo, acc);

  // stage elu(k)|v into Kt/Vt [256][68] (2-way max on frag reads)
  bf16* Kt = smem;
  bf16* Vt = smem + 17408;
  {
    bf16* T = wn ? Vt : Kt;
#pragma unroll
    for (int mf = 0; mf < 8; ++mf)
#pragma unroll
      for (int nf = 0; nf < 4; ++nf)
#pragma unroll
        for (int r = 0; r < 4; ++r) {
          float v = acc[mf][nf][r];
          if (wn == 0) v = (v > 0.f) ? (v + 1.f) : __expf(v);
          T[(wm * 128 + mf * 16 + grp * 4 + r) * 68 + nf * 16 + mlane] = (bf16)v;
        }
  }
  __syncthreads();

  f32x4 akv[4][4], a5[4];
#pragma unroll
  for (int i = 0; i < 4; ++i) {
    a5[i] = zero;
#pragma unroll
    for (int j = 0; j < 4; ++j) akv[i][j] = zero;
  }
  bf16x8 ones;
#pragma unroll
  for (int jj = 0; jj < 8; ++jj) ones[jj] = (bf16)1.0f;

#pragma unroll
  for (int c = 0; c < 2; ++c) {
    const int sw = w * 64 + c * 32;
    bf16x8 av[4], bk[4];
#pragma unroll
    for (int jj = 0; jj < 8; ++jj) {
      const bf16* vr = &Vt[(sw + grp * 8 + jj) * 68];
      const bf16* kr = &Kt[(sw + grp * 8 + jj) * 68];
#pragma unroll
      for (int i = 0; i < 4; ++i) av[i][jj] = vr[i * 16 + mlane];
#pragma unroll
      for (int j = 0; j < 4; ++j) bk[j][jj] = kr[j * 16 + mlane];
    }
#pragma unroll
    for (int i = 0; i < 4; ++i)
#pragma unroll
      for (int j = 0; j < 4; ++j) akv[i][j] = MFMA(av[i], bk[j], akv[i][j]);
#pragma unroll
    for (int j = 0; j < 4; ++j) a5[j] = MFMA(ones, bk[j], a5[j]);
  }
  __syncthreads();

  // 4-wave tree reduce in LDS (Kt/Vt dead)
  float* Pr = (float*)smem;        // [2][4096]
  float* Kr = Pr + 8192;           // [2][64]
  if (w >= 2) {
#pragma unroll
    for (int i = 0; i < 4; ++i)
#pragma unroll
      for (int j = 0; j < 4; ++j)
#pragma unroll
        for (int r = 0; r < 4; ++r)
          Pr[(w - 2) * 4096 + (i * 16 + grp * 4 + r) * 64 + j * 16 + mlane] =
              akv[i][j][r];
    if (grp == 0) {
#pragma unroll
      for (int j = 0; j < 4; ++j) Kr[(w - 2) * 64 + j * 16 + mlane] = a5[j][0];
    }
  }
  __syncthreads();
  if (w < 2) {
#pragma unroll
    for (int i = 0; i < 4; ++i)
#pragma unroll
      for (int j = 0; j < 4; ++j)
#pragma unroll
        for (int r = 0; r < 4; ++r)
          akv[i][j][r] += Pr[w * 4096 + (i * 16 + grp * 4 + r) * 64 + j * 16 + mlane];
    if (grp == 0) {
#pragma unroll
      for (int j = 0; j < 4; ++j) a5[j][0] += Kr[w * 64 + j * 16 + mlane];
    }
  }
  __syncthreads();
  if (w == 1) {
#pragma unroll
    for (int i = 0; i < 4; ++i)
#pragma unroll
      for (int j = 0; j < 4; ++j)
#pragma unroll
        for (int r = 0; r < 4; ++r)
          Pr[(i * 16 + grp * 4 + r) * 64 + j * 16 + mlane] = akv[i][j][r];
    if (grp == 0) {
#pragma unroll
      for (int j = 0; j < 4; ++j) Kr[j * 16 + mlane] = a5[j][0];
    }
  }
  __syncthreads();
  if (w == 0) {
    const int widx = rt * 16 + h;
    float* pw = Pp + (size_t)widx * 4096;
#pragma unroll
    for (int i = 0; i < 4; ++i)
#pragma unroll
      for (int j = 0; j < 4; ++j)
#pragma unroll
        for (int r = 0; r < 4; ++r)
          pw[(i * 16 + grp * 4 + r) * 64 + j * 16 + mlane] =
              akv[i][j][r] + Pr[(i * 16 + grp * 4 + r) * 64 + j * 16 + mlane];
    if (grp == 0) {
#pragma unroll
      for (int j = 0; j < 4; ++j)
        KsP[(size_t)widx * 64 + j * 16 + mlane] =
            a5[j][0] + Kr[j * 16 + mlane];
    }
  }
}

// ----------------------------------------------------------------- reduce ---
__global__ __launch_bounds__(256) void reduce_kv2(
    const float* __restrict__ Pp, const float* __restrict__ KsP,
    bf16* __restrict__ kvb, bf16* __restrict__ ksb) {
  const int bh = blockIdx.x, y = blockIdx.y, tid = threadIdx.x;
  const int b = bh >> 4, h = bh & 15;
  if (y < 16) {
    const int o = y * 256 + tid;
    float s = 0.f;
#pragma unroll
    for (int i = 0; i < 32; ++i)
      s += Pp[(size_t)((b * 32 + i) * 16 + h) * 4096 + o];
    kvb[(size_t)bh * 4096 + o] = (bf16)s;
  } else if (tid < 64) {
    float s = 0.f;
#pragma unroll
    for (int i = 0; i < 32; ++i)
      s += KsP[(size_t)((b * 32 + i) * 16 + h) * 64 + tid];
    ksb[bh * 64 + tid] = (bf16)s;
  }
}

// ----------------------------------------------------------------- qattn ----
// grid 1024 = 128 rt x 8 ct (ct fastest). Wave = one head (head = ct*2+wn).
// Epilogue: elu->bf16->Qs (XOR-swizzled [64][64])->q@kv + normalizer -> attn.
__global__ __launch_bounds__(256, 2) void gemm_qattn(
    const bf16* __restrict__ xb, const bf16* __restrict__ wbq,
    const bf16* __restrict__ kvb, const bf16* __restrict__ ksb,
    bf16* __restrict__ attn) {
  __shared__ __align__(16) bf16 smem[36864];
  const int tid = threadIdx.x;
  const int w = tid >> 6, lane = tid & 63;
  const int grp = lane >> 4, mlane = lane & 15;
  const int wm = w >> 1, wn = w & 1;

  int bid = (int)blockIdx.x;
  const int cpx = (int)gridDim.x >> 3;
  bid = (bid & 7) * cpx + (bid >> 3);
  const int ct = bid & 7, rt = bid >> 3;
  const int rowA0 = rt * 256;

  const int lrr = tid >> 2;
  const int lcs = (tid & 3) ^ ((tid >> 3) & 3);
  const bf16* pA  = xb + (size_t)(rowA0 + lrr) * 1024 + lcs * 8;
  const bf16* pB0 = wbq + (size_t)(ct * 128 + lrr) * 1024 + lcs * 8;
  const bf16* pB1 = pB0 + (size_t)64 * 1024;
  const int cgo = (grp ^ ((mlane >> 1) & 3)) * 8;
  const int arow = wm * 128 + mlane;
  const int brow = wn * 64 + mlane;

  const f32x4 zero = {0.f, 0.f, 0.f, 0.f};
  f32x4 acc[8][4];
#pragma unroll
  for (int i = 0; i < 8; ++i)
#pragma unroll
    for (int j = 0; j < 4; ++j) acc[i][j] = zero;

  kloop(smem, pA, pB0, pB1, tid, arow, brow, cgo, acc);

  // per-head kv / ksum fragments (tiny, L2-hot)
  const int head = ct * 2 + wn;
  const int bh = (rt >> 5) * 16 + head;
  bf16x8 bkv[2][4], b5v[2];
#pragma unroll
  for (int ks = 0; ks < 2; ++ks) {
#pragma unroll
    for (int nf = 0; nf < 4; ++nf)
      bkv[ks][nf] = *(const bf16x8*)&kvb[(size_t)bh * 4096 +
                                         (nf * 16 + mlane) * 64 + ks * 32 + grp * 8];
    b5v[ks] = *(const bf16x8*)&ksb[bh * 64 + ks * 32 + grp * 8];
  }

  // wave-private Qs [64][64] with 3-bit granule XOR swizzle (stride 128B)
  bf16* Qs = smem + w * 4096;
  const int swr = (mlane >> 1) & 7;  // read-side swizzle (row = i*16+mlane)
#pragma unroll
  for (int mh = 0; mh < 2; ++mh) {
#pragma unroll
    for (int i = 0; i < 4; ++i)
#pragma unroll
      for (int nf = 0; nf < 4; ++nf)
#pragma unroll
        for (int r = 0; r < 4; ++r) {
          float v = acc[mh * 4 + i][nf][r];
          v = (v > 0.f) ? (v + 1.f) : __expf(v);
          const int rw = i * 16 + grp * 4 + r;
          const int d = nf * 16 + mlane;
          Qs[rw * 64 + (((d >> 3) ^ ((rw >> 1) & 7)) << 3) + (d & 7)] = (bf16)v;
        }
    bf16x8 aq2[4][2];
#pragma unroll
    for (int i = 0; i < 4; ++i)
#pragma unroll
      for (int ks = 0; ks < 2; ++ks)
        aq2[i][ks] = *(const bf16x8*)&Qs[(i * 16 + mlane) * 64 +
                                         (((ks * 4 + grp) ^ swr) << 3)];
    f32x4 ao[4][4], a5q[4];
#pragma unroll
    for (int i = 0; i < 4; ++i) {
      a5q[i] = zero;
#pragma unroll
      for (int nf = 0; nf < 4; ++nf) ao[i][nf] = zero;
    }
#pragma unroll
    for (int ks = 0; ks < 2; ++ks)
#pragma unroll
      for (int i = 0; i < 4; ++i) {
#pragma unroll
        for (int nf = 0; nf < 4; ++nf)
          ao[i][nf] = MFMA(aq2[i][ks], bkv[ks][nf], ao[i][nf]);
        a5q[i] = MFMA(aq2[i][ks], b5v[ks], a5q[i]);
      }
#pragma unroll
    for (int i = 0; i < 4; ++i)
#pragma unroll
      for (int r = 0; r < 4; ++r) {
        const float inv = 1.0f / fmaxf(a5q[i][r], 1e-6f);
        bf16* op = attn + (size_t)(rowA0 + wm * 128 + mh * 64 + i * 16 +
                                   grp * 4 + r) * 1024 + head * 64;
#pragma unroll
        for (int nf = 0; nf < 4; ++nf)
          op[nf * 16 + mlane] = (bf16)(ao[i][nf][r] * inv);
      }
  }
}

// ------------------------------------------------------------------- out ----
// grid 1024 = 128 rt x 8 ct. C f32 directly into d_out.
__global__ __launch_bounds__(256, 2) void gemm_out(
    const bf16* __restrict__ attn, const bf16* __restrict__ wbo,
    float* __restrict__ C) {
  __shared__ __align__(16) bf16 smem[36864];
  const int tid = threadIdx.x;
  const int w = tid >> 6, lane = tid & 63;
  const int grp = lane >> 4, mlane = lane & 15;
  const int wm = w >> 1, wn = w & 1;

  int bid = (int)blockIdx.x;
  const int cpx = (int)gridDim.x >> 3;
  bid = (bid & 7) * cpx + (bid >> 3);
  const int ct = bid & 7, rt = bid >> 3;
  const int rowA0 = rt * 256;

  const int lrr = tid >> 2;
  const int lcs = (tid & 3) ^ ((tid >> 3) & 3);
  const bf16* pA  = attn + (size_t)(rowA0 + lrr) * 1024 + lcs * 8;
  const bf16* pB0 = wbo + (size_t)(ct * 128 + lrr) * 1024 + lcs * 8;
  const bf16* pB1 = pB0 + (size_t)64 * 1024;
  const int cgo = (grp ^ ((mlane >> 1) & 3)) * 8;
  const int arow = wm * 128 + mlane;
  const int brow = wn * 64 + mlane;

  const f32x4 zero = {0.f, 0.f, 0.f, 0.f};
  f32x4 acc[8][4];
#pragma unroll
  for (int i = 0; i < 8; ++i)
#pragma unroll
    for (int j = 0; j < 4; ++j) acc[i][j] = zero;

  kloop(smem, pA, pB0, pB1, tid, arow, brow, cgo, acc);

#pragma unroll
  for (int mf = 0; mf < 8; ++mf)
#pragma unroll
    for (int nf = 0; nf < 4; ++nf) {
      float* cp = C + (size_t)(rowA0 + wm * 128 + mf * 16 + grp * 4) * 1024 +
                  ct * 128 + wn * 64 + nf * 16 + mlane;
#pragma unroll
      for (int r = 0; r < 4; ++r) cp[(size_t)r * 1024] = acc[mf][nf][r];
    }
}

// ----------------------------------------------------------------- launch ---
extern "C" void kernel_launch(void* const* d_in, const int* in_sizes, int n_in,
                              void* d_out, int out_size, void* d_ws, size_t ws_size,
                              hipStream_t stream) {
  const float* x     = (const float*)d_in[0];
  const float* w_qkv = (const float*)d_in[1];
  const float* w_out = (const float*)d_in[2];
  char* O  = (char*)d_out;
  char* A  = (char*)d_in[0];
  char* W1 = (char*)d_in[1];

  bf16*  xb   = (bf16*)O;                       // [32768][1024]
  bf16*  wbq  = (bf16*)(O + 67108864);          // [3072][1024]
  float* Pp   = (float*)(O + 75497472);         // [2048][4096] f32
  float* KsP  = (float*)(O + 109051904);        // [2048][64] f32
  bf16*  attn = (bf16*)A;                       // over x (dead after cvt)
  bf16*  wbo  = (bf16*)W1;                      // [1024][1024]
  bf16*  kvb  = (bf16*)(W1 + 2097152);          // [64][4096]
  bf16*  ksb  = (bf16*)(W1 + 2621440);          // [64][64]

  cvt_bf16<<<2048, 256, 0, stream>>>(x, xb, 4194304);
  cvt_bf16<<<1536, 256, 0, stream>>>(w_qkv, wbq, 393216);
  cvt_bf16<<<512, 256, 0, stream>>>(w_out, wbo, 131072);
  gemm_kvfold<<<2048, 256, 0, stream>>>(xb, wbq, Pp, KsP);
  reduce_kv2<<<dim3(64, 17), 256, 0, stream>>>(Pp, KsP, kvb, ksb);
  gemm_qattn<<<1024, 256, 0, stream>>>(xb, wbq, kvb, ksb, attn);
  gemm_out<<<1024, 256, 0, stream>>>(attn, wbo, (float*)O);
}